// Round 10
// baseline (410.427 us; speedup 1.0000x reference)
//
#include <hip/hip_runtime.h>
#include <math.h>

typedef __attribute__((ext_vector_type(8))) short bf16x8;
typedef __attribute__((ext_vector_type(4))) float f32x4;

constexpr int D = 256;           // feature dim (K of GEMM)
constexpr int H = 128;           // hidden dim
constexpr int KSTEPS = D / 32;   // 8 MFMA k-steps
constexpr int BM = 128;          // rows per block
constexpr int NPB3 = 64;         // nodes per block, pass 3

__device__ __forceinline__ unsigned int enc_f(float f) {
  unsigned int b = __float_as_uint(f);
  return (b & 0x80000000u) ? ~b : (b | 0x80000000u);
}
__device__ __forceinline__ float dec_f(unsigned int u) {
  return __uint_as_float((u & 0x80000000u) ? (u ^ 0x80000000u) : ~u);
}
__device__ __forceinline__ float trunc_bf(float a) {
  return __uint_as_float(__float_as_uint(a) & 0xFFFF0000u);
}
__device__ __forceinline__ unsigned int pack2_bf(float a, float b) {
  return (__float_as_uint(a) >> 16) | (__float_as_uint(b) & 0xFFFF0000u);
}

union FragU { uint4 u; bf16x8 f; };

__device__ __forceinline__ void gload16(const void* g, void* l) {
  __builtin_amdgcn_global_load_lds(
      (const __attribute__((address_space(1))) unsigned int*)g,
      (__attribute__((address_space(3))) unsigned int*)l, 16, 0, 0);
}
__device__ __forceinline__ void block_sync() {
  asm volatile("" ::: "memory");
  __builtin_amdgcn_s_barrier();
  asm volatile("" ::: "memory");
}

// ---- Pre-pack W1 into per-lane MFMA B-fragment order (hi/lo bf16) ----------
extern "C" __global__ void __launch_bounds__(256)
k_pack(const float* __restrict__ W1, uint4* __restrict__ phi,
       uint4* __restrict__ plo)
{
  const int g = blockIdx.x * 256 + threadIdx.x;       // 0..4095
  const int c = g >> 9, ht = (g >> 6) & 7, l = g & 63;
  const int kbase = c * 32 + (l >> 4) * 8;
  const int col = ht * 16 + (l & 15);
  float v[8], lo[8];
#pragma unroll
  for (int i = 0; i < 8; ++i) {
    v[i] = W1[(size_t)(kbase + i) * H + col];
    lo[i] = v[i] - trunc_bf(v[i]);
  }
  uint4 h4, l4;
  h4.x = pack2_bf(v[0], v[1]); h4.y = pack2_bf(v[2], v[3]);
  h4.z = pack2_bf(v[4], v[5]); h4.w = pack2_bf(v[6], v[7]);
  l4.x = pack2_bf(lo[0], lo[1]); l4.y = pack2_bf(lo[2], lo[3]);
  l4.z = pack2_bf(lo[4], lo[5]); l4.w = pack2_bf(lo[6], lo[7]);
  phi[g] = h4; plo[g] = l4;
}

// ---- Pass 1 (REAL, R5 verbatim): 2-phase LDS pipeline ----------------------
extern "C" __global__ void __launch_bounds__(256, 2)
k_scores_mfma(const float* __restrict__ x, const uint4* __restrict__ phi,
              const uint4* __restrict__ plo, const float* __restrict__ b1,
              const float* __restrict__ W2, const float* __restrict__ b2,
              float* __restrict__ scores, unsigned int* __restrict__ gmax, int N)
{
  __shared__ float4 xplane[2][1024];
  __shared__ uint4 btile[2][1024];
  __shared__ float sred[2][BM];

  const int t = threadIdx.x;
  const int l = t & 63;
  const int w = t >> 6;
  const int lg = l >> 4;
  const int lr = l & 15;
  const int rg = w >> 1;
  const int cg = w & 1;
  const int n0 = blockIdx.x * BM;

  const char* xb = (const char*)x;
  const char* phib = (const char*)phi;
  const char* plob = (const char*)plo;

  auto STAGE = [&](int buf, int c) {
#pragma unroll
    for (int i = 0; i < 4; ++i) {
      const int plane = i * 4 + w;
      const int g = plane >> 1, p = plane & 1;
      const int srow = min(n0 + g * 16 + lr, N - 1);
      gload16(xb + (size_t)srow * 1024 + c * 128 + lg * 32 + p * 16,
              (char*)&xplane[buf][plane * 64 + l]);
    }
    char* bd = (char*)&btile[buf][0];
#pragma unroll
    for (int i = 0; i < 2; ++i) {
      const int off = i * 4096 + t * 16;
      gload16(phib + c * 8192 + off, bd + off);
      gload16(plob + c * 8192 + off, bd + 8192 + off);
    }
  };

  f32x4 acc[4][4] = {};

  STAGE(0, 0);
#pragma unroll 1
  for (int c = 0; c < KSTEPS; ++c) {
    const int cur = c & 1;
    if (c + 1 < KSTEPS) {
      STAGE(cur ^ 1, c + 1);
      asm volatile("s_waitcnt vmcnt(8)" ::: "memory");
    } else {
      asm volatile("s_waitcnt vmcnt(0)" ::: "memory");
    }
    block_sync();

    FragU bhi[4], blo[4];
#pragma unroll
    for (int h = 0; h < 4; ++h) {
      const int ht = cg * 4 + h;
      bhi[h].u = btile[cur][ht * 64 + l];
      blo[h].u = btile[cur][512 + ht * 64 + l];
    }
#pragma unroll
    for (int s = 0; s < 4; ++s) {
      const int g = rg * 4 + s;
      const float4 u0 = xplane[cur][(g * 2 + 0) * 64 + l];
      const float4 u1 = xplane[cur][(g * 2 + 1) * 64 + l];
      float v[8], lo[8];
      v[0] = u0.x; v[1] = u0.y; v[2] = u0.z; v[3] = u0.w;
      v[4] = u1.x; v[5] = u1.y; v[6] = u1.z; v[7] = u1.w;
#pragma unroll
      for (int i = 0; i < 8; ++i) lo[i] = v[i] - trunc_bf(v[i]);
      FragU ahi, alo;
      ahi.u.x = pack2_bf(v[0], v[1]);  ahi.u.y = pack2_bf(v[2], v[3]);
      ahi.u.z = pack2_bf(v[4], v[5]);  ahi.u.w = pack2_bf(v[6], v[7]);
      alo.u.x = pack2_bf(lo[0], lo[1]); alo.u.y = pack2_bf(lo[2], lo[3]);
      alo.u.z = pack2_bf(lo[4], lo[5]); alo.u.w = pack2_bf(lo[6], lo[7]);
#pragma unroll
      for (int h = 0; h < 4; ++h) {
        acc[s][h] = __builtin_amdgcn_mfma_f32_16x16x32_bf16(ahi.f, bhi[h].f, acc[s][h], 0, 0, 0);
        acc[s][h] = __builtin_amdgcn_mfma_f32_16x16x32_bf16(ahi.f, blo[h].f, acc[s][h], 0, 0, 0);
        acc[s][h] = __builtin_amdgcn_mfma_f32_16x16x32_bf16(alo.f, bhi[h].f, acc[s][h], 0, 0, 0);
      }
    }
    block_sync();
  }

  float bvv[4], wvv[4];
#pragma unroll
  for (int h = 0; h < 4; ++h) {
    const int col = (cg * 4 + h) * 16 + lr;
    bvv[h] = b1[col];
    wvv[h] = W2[col];
  }
#pragma unroll
  for (int s = 0; s < 4; ++s) {
#pragma unroll
    for (int r = 0; r < 4; ++r) {
      float p = 0.0f;
#pragma unroll
      for (int h = 0; h < 4; ++h)
        p = fmaf(fmaxf(acc[s][h][r] + bvv[h], 0.0f), wvv[h], p);
#pragma unroll
      for (int off = 1; off < 16; off <<= 1) p += __shfl_xor(p, off, 64);
      if (lr == 0) sred[cg][rg * 64 + s * 16 + lg * 4 + r] = p;
    }
  }
  __syncthreads();
  if (cg == 0) {
    const int row = rg * 64 + l;
    const int node = n0 + row;
    const float sc = sred[0][row] + sred[1][row] + b2[0];
    float mym = -INFINITY;
    if (node < N) { scores[node] = sc; mym = sc; }
#pragma unroll
    for (int off = 1; off < 64; off <<= 1)
      mym = fmaxf(mym, __shfl_xor(mym, off, 64));
    if (l == 0) atomicMax(gmax, enc_f(mym));
  }
}

// ---- PROBE: identical structure, x windowed to L2-hot 2MB, REP=3 -----------
// Measures the structural ceiling of the R5 pipeline with memory supply
// removed from the equation. Runs LAST; writes only to scratch.
extern "C" __global__ void __launch_bounds__(256, 2)
p_mlpc(const float* __restrict__ x, const uint4* __restrict__ phi,
       const uint4* __restrict__ plo, const float* __restrict__ b1,
       const float* __restrict__ W2, const float* __restrict__ b2,
       float* __restrict__ pscratch, unsigned int* __restrict__ gmax, int N)
{
  __shared__ float4 xplane[2][1024];
  __shared__ uint4 btile[2][1024];
  __shared__ float sred[2][BM];

  const int t = threadIdx.x;
  const int l = t & 63;
  const int w = t >> 6;
  const int lg = l >> 4;
  const int lr = l & 15;
  const int rg = w >> 1;
  const int cg = w & 1;
  const int n0 = (blockIdx.x & 15) * BM;   // 2 MB hot window (rows 0..2047)

  const char* xb = (const char*)x;
  const char* phib = (const char*)phi;
  const char* plob = (const char*)plo;

  auto STAGE = [&](int buf, int c) {
#pragma unroll
    for (int i = 0; i < 4; ++i) {
      const int plane = i * 4 + w;
      const int g = plane >> 1, p = plane & 1;
      const int srow = min(n0 + g * 16 + lr, N - 1);
      gload16(xb + (size_t)srow * 1024 + c * 128 + lg * 32 + p * 16,
              (char*)&xplane[buf][plane * 64 + l]);
    }
    char* bd = (char*)&btile[buf][0];
#pragma unroll
    for (int i = 0; i < 2; ++i) {
      const int off = i * 4096 + t * 16;
      gload16(phib + c * 8192 + off, bd + off);
      gload16(plob + c * 8192 + off, bd + 8192 + off);
    }
  };

  f32x4 acc[4][4] = {};

#pragma unroll 1
  for (int rep = 0; rep < 3; ++rep) {
    STAGE(0, 0);
#pragma unroll 1
    for (int c = 0; c < KSTEPS; ++c) {
      const int cur = c & 1;
      if (c + 1 < KSTEPS) {
        STAGE(cur ^ 1, c + 1);
        asm volatile("s_waitcnt vmcnt(8)" ::: "memory");
      } else {
        asm volatile("s_waitcnt vmcnt(0)" ::: "memory");
      }
      block_sync();

      FragU bhi[4], blo[4];
#pragma unroll
      for (int h = 0; h < 4; ++h) {
        const int ht = cg * 4 + h;
        bhi[h].u = btile[cur][ht * 64 + l];
        blo[h].u = btile[cur][512 + ht * 64 + l];
      }
#pragma unroll
      for (int s = 0; s < 4; ++s) {
        const int g = rg * 4 + s;
        const float4 u0 = xplane[cur][(g * 2 + 0) * 64 + l];
        const float4 u1 = xplane[cur][(g * 2 + 1) * 64 + l];
        float v[8], lo[8];
        v[0] = u0.x; v[1] = u0.y; v[2] = u0.z; v[3] = u0.w;
        v[4] = u1.x; v[5] = u1.y; v[6] = u1.z; v[7] = u1.w;
#pragma unroll
        for (int i = 0; i < 8; ++i) lo[i] = v[i] - trunc_bf(v[i]);
        FragU ahi, alo;
        ahi.u.x = pack2_bf(v[0], v[1]);  ahi.u.y = pack2_bf(v[2], v[3]);
        ahi.u.z = pack2_bf(v[4], v[5]);  ahi.u.w = pack2_bf(v[6], v[7]);
        alo.u.x = pack2_bf(lo[0], lo[1]); alo.u.y = pack2_bf(lo[2], lo[3]);
        alo.u.z = pack2_bf(lo[4], lo[5]); alo.u.w = pack2_bf(lo[6], lo[7]);
#pragma unroll
        for (int h = 0; h < 4; ++h) {
          acc[s][h] = __builtin_amdgcn_mfma_f32_16x16x32_bf16(ahi.f, bhi[h].f, acc[s][h], 0, 0, 0);
          acc[s][h] = __builtin_amdgcn_mfma_f32_16x16x32_bf16(ahi.f, blo[h].f, acc[s][h], 0, 0, 0);
          acc[s][h] = __builtin_amdgcn_mfma_f32_16x16x32_bf16(alo.f, bhi[h].f, acc[s][h], 0, 0, 0);
        }
      }
      block_sync();
    }
  }

  float bvv[4], wvv[4];
#pragma unroll
  for (int h = 0; h < 4; ++h) {
    const int col = (cg * 4 + h) * 16 + lr;
    bvv[h] = b1[col];
    wvv[h] = W2[col];
  }
#pragma unroll
  for (int s = 0; s < 4; ++s) {
#pragma unroll
    for (int r = 0; r < 4; ++r) {
      float p = 0.0f;
#pragma unroll
      for (int h = 0; h < 4; ++h)
        p = fmaf(fmaxf(acc[s][h][r] + bvv[h], 0.0f), wvv[h], p);
#pragma unroll
      for (int off = 1; off < 16; off <<= 1) p += __shfl_xor(p, off, 64);
      if (lr == 0) sred[cg][rg * 64 + s * 16 + lg * 4 + r] = p;
    }
  }
  __syncthreads();
  if (cg == 0) {
    const int row = rg * 64 + l;
    const float sc = sred[0][row] + sred[1][row] + b2[0];
    pscratch[n0 + row] = sc;   // same value for all blocks sharing window: deterministic
  }
}

// ---- Pass 2: Z = sum(exp(s - max)) -----------------------------------------
extern "C" __global__ void __launch_bounds__(256)
k_expsum(const float* __restrict__ scores, const unsigned int* __restrict__ gmax,
         float* __restrict__ zacc, int N)
{
  const float m = dec_f(*gmax);
  float sum = 0.0f;
  for (int i = blockIdx.x * blockDim.x + threadIdx.x; i < N;
       i += gridDim.x * blockDim.x)
    sum += __expf(scores[i] - m);
#pragma unroll
  for (int off = 32; off > 0; off >>= 1) sum += __shfl_down(sum, off, 64);
  __shared__ float wred[4];
  if ((threadIdx.x & 63) == 0) wred[threadIdx.x >> 6] = sum;
  __syncthreads();
  if (threadIdx.x == 0)
    atomicAdd(zacc, wred[0] + wred[1] + wred[2] + wred[3]);
}

// ---- Pass 3: pooled[b] += x[n] * w[n] (batch sorted) -----------------------
extern "C" __global__ void __launch_bounds__(64)
k_pool(const float* __restrict__ x, const int* __restrict__ batch,
       const float* __restrict__ scores, const unsigned int* __restrict__ gmax,
       const float* __restrict__ zacc, float* __restrict__ out, int N)
{
  const int t = threadIdx.x;
  const int n0 = blockIdx.x * NPB3;
  const int n1 = min(n0 + NPB3, N);
  if (n0 >= n1) return;
  const float m = dec_f(*gmax);
  const float invZ = 1.0f / (*zacc);

  float4 acc = make_float4(0.f, 0.f, 0.f, 0.f);
  int bprev = batch[n0];
  for (int n = n0; n < n1; ++n) {
    const int b = batch[n];
    if (b != bprev) {
      float* o = out + (size_t)bprev * D + t * 4;
      atomicAdd(o + 0, acc.x); atomicAdd(o + 1, acc.y);
      atomicAdd(o + 2, acc.z); atomicAdd(o + 3, acc.w);
      acc = make_float4(0.f, 0.f, 0.f, 0.f);
      bprev = b;
    }
    const float wgt = __expf(scores[n] - m) * invZ;
    const float4 xv = *reinterpret_cast<const float4*>(x + (size_t)n * D + t * 4);
    acc.x = fmaf(xv.x, wgt, acc.x);
    acc.y = fmaf(xv.y, wgt, acc.y);
    acc.z = fmaf(xv.z, wgt, acc.z);
    acc.w = fmaf(xv.w, wgt, acc.w);
  }
  float* o = out + (size_t)bprev * D + t * 4;
  atomicAdd(o + 0, acc.x); atomicAdd(o + 1, acc.y);
  atomicAdd(o + 2, acc.z); atomicAdd(o + 3, acc.w);
}

extern "C" void kernel_launch(void* const* d_in, const int* in_sizes, int n_in,
                              void* d_out, int out_size, void* d_ws, size_t ws_size,
                              hipStream_t stream)
{
  const float* x     = (const float*)d_in[0];
  const int*   batch = (const int*)d_in[1];
  const float* W1 = (const float*)d_in[3];
  const float* b1 = (const float*)d_in[4];
  const float* W2 = (const float*)d_in[5];
  const float* b2 = (const float*)d_in[6];
  const int N = in_sizes[1];

  unsigned int* gmax = (unsigned int*)d_ws;
  float* zacc        = (float*)((char*)d_ws + 64);
  uint4* phi         = (uint4*)((char*)d_ws + 256);            // 64 KB
  uint4* plo         = (uint4*)((char*)d_ws + 256 + 65536);    // 64 KB
  float* scores      = (float*)((char*)d_ws + 256 + 131072);   // N floats

  hipMemsetAsync(d_out, 0, (size_t)out_size * sizeof(float), stream);
  hipMemsetAsync(d_ws, 0, 256, stream);

  k_pack<<<16, 256, 0, stream>>>(W1, phi, plo);

  const int g1 = (N + BM - 1) / BM;
  k_scores_mfma<<<g1, 256, 0, stream>>>(x, phi, plo, b1, W2, b2, scores, gmax, N);

  int g2 = (N + 255) / 256; if (g2 > 2048) g2 = 2048;
  k_expsum<<<g2, 256, 0, stream>>>(scores, gmax, zacc, N);

  const int g3 = (N + NPB3 - 1) / NPB3;
  k_pool<<<g3, 64, 0, stream>>>(x, batch, scores, gmax, zacc, (float*)d_out, N);

  // probe LAST: overwrites only the (now-consumed) scores region + gmax slot
  p_mlpc<<<g1, 256, 0, stream>>>(x, phi, plo, b1, W2, b2, scores, gmax, N);
}

// Round 11
// 170.419 us; speedup vs baseline: 2.4083x; 2.4083x over previous
//
#include <hip/hip_runtime.h>
#include <math.h>

typedef __attribute__((ext_vector_type(8))) short bf16x8;
typedef __attribute__((ext_vector_type(4))) float f32x4;

constexpr int D = 256;           // feature dim (K of GEMM)
constexpr int H = 128;           // hidden dim
constexpr int KSTEPS = D / 32;   // 8 MFMA k-steps
constexpr int BM = 128;          // rows per block

__device__ __forceinline__ float trunc_bf(float a) {
  return __uint_as_float(__float_as_uint(a) & 0xFFFF0000u);
}
__device__ __forceinline__ unsigned int pack2_bf(float a, float b) {
  return (__float_as_uint(a) >> 16) | (__float_as_uint(b) & 0xFFFF0000u);
}
// round-to-nearest bf16 pack (for A: halves the magnitude of the dropped term)
__device__ __forceinline__ unsigned int pack2_bf_rnd(float a, float b) {
  return ((__float_as_uint(a) + 0x8000u) >> 16) |
         ((__float_as_uint(b) + 0x8000u) & 0xFFFF0000u);
}

union FragU { uint4 u; bf16x8 f; };

__device__ __forceinline__ void gload16(const void* g, void* l) {
  __builtin_amdgcn_global_load_lds(
      (const __attribute__((address_space(1))) unsigned int*)g,
      (__attribute__((address_space(3))) unsigned int*)l, 16, 0, 0);
}
__device__ __forceinline__ void block_sync() {
  asm volatile("" ::: "memory");
  __builtin_amdgcn_s_barrier();
  asm volatile("" ::: "memory");
}

// ---- init: zero d_out + Z accumulator --------------------------------------
extern "C" __global__ void __launch_bounds__(256)
k_init(float* __restrict__ out, int out_size, float* __restrict__ zacc)
{
  const int i = blockIdx.x * 256 + threadIdx.x;
  if (i < out_size) out[i] = 0.0f;
  if (i == 0) *zacc = 0.0f;
}

// ---- Pre-pack W1 into per-lane MFMA B-fragment order (hi/lo bf16) ----------
// W keeps BOTH hi and lo (exact split); A-side lo is dropped (rounded A).
extern "C" __global__ void __launch_bounds__(256)
k_pack(const float* __restrict__ W1, uint4* __restrict__ phi,
       uint4* __restrict__ plo)
{
  const int g = blockIdx.x * 256 + threadIdx.x;       // 0..4095
  const int c = g >> 9, ht = (g >> 6) & 7, l = g & 63;
  const int kbase = c * 32 + (l >> 4) * 8;
  const int col = ht * 16 + (l & 15);
  float v[8], lo[8];
#pragma unroll
  for (int i = 0; i < 8; ++i) {
    v[i] = W1[(size_t)(kbase + i) * H + col];
    lo[i] = v[i] - trunc_bf(v[i]);
  }
  uint4 h4, l4;
  h4.x = pack2_bf(v[0], v[1]); h4.y = pack2_bf(v[2], v[3]);
  h4.z = pack2_bf(v[4], v[5]); h4.w = pack2_bf(v[6], v[7]);
  l4.x = pack2_bf(lo[0], lo[1]); l4.y = pack2_bf(lo[2], lo[3]);
  l4.z = pack2_bf(lo[4], lo[5]); l4.w = pack2_bf(lo[6], lo[7]);
  phi[g] = h4; plo[g] = l4;
}

// ---- Fused: scores (MFMA) -> w = exp(s) -> weighted pool of own rows -------
// R6 structure; changes: A-side lo dropped (rounded A, 2 MFMAs per frag),
// launch_bounds(256,4) for 4 blocks/CU.
extern "C" __global__ void __launch_bounds__(256, 4)
k_fused(const float* __restrict__ x, const int* __restrict__ batch,
        const uint4* __restrict__ phi, const uint4* __restrict__ plo,
        const float* __restrict__ b1, const float* __restrict__ W2,
        const float* __restrict__ b2, float* __restrict__ out,
        float* __restrict__ zacc, int N)
{
  __shared__ float4 xplane[2][1024];   // 16 planes x 64 lanes x 16 B = 16 KB/buf
  __shared__ float sred[2][BM];        // cross-wave epilogue partials
  __shared__ float wlds[BM];           // per-row unnormalized weights

  const int t = threadIdx.x;
  const int l = t & 63;
  const int w = t >> 6;
  const int lg = l >> 4;      // k-group (0..3)
  const int lr = l & 15;      // M-row (A) / N-col (B,C)
  const int rg = w >> 1;      // row half (0..1)
  const int cg = w & 1;       // col half (0..1)
  const int n0 = blockIdx.x * BM;

  const char* xb = (const char*)x;

  // stage x tile for kstep c into buffer buf (4 gload16 per thread)
  auto STAGE = [&](int buf, int c) {
#pragma unroll
    for (int i = 0; i < 4; ++i) {
      const int plane = i * 4 + w;
      const int g = plane >> 1, p = plane & 1;
      const int srow = min(n0 + g * 16 + lr, N - 1);   // clamp OOB (discarded)
      gload16(xb + (size_t)srow * 1024 + c * 128 + lg * 32 + p * 16,
              (char*)&xplane[buf][plane * 64 + l]);
    }
  };

  f32x4 acc[4][4] = {};   // [stripe s][local htile h]

  STAGE(0, 0);
#pragma unroll 1
  for (int c = 0; c < KSTEPS; ++c) {
    const int cur = c & 1;
    // B fragments for this wave's 4 htiles -> registers (L2-resident)
    FragU bhi[4], blo[4];
#pragma unroll
    for (int h = 0; h < 4; ++h) {
      const int ht = cg * 4 + h;
      bhi[h].u = phi[(c * 8 + ht) * 64 + l];
      blo[h].u = plo[(c * 8 + ht) * 64 + l];
    }
    if (c + 1 < KSTEPS) {
      STAGE(cur ^ 1, c + 1);
      // older [B(c):8 + STAGE(c):<=4] drained; only STAGE(c+1) in flight
      asm volatile("s_waitcnt vmcnt(4)" ::: "memory");
    } else {
      asm volatile("s_waitcnt vmcnt(0)" ::: "memory");
    }
    block_sync();

    // A fragments per stripe (conflict-free plane reads), round-pack, MFMA x2
#pragma unroll
    for (int s = 0; s < 4; ++s) {
      const int g = rg * 4 + s;
      const float4 u0 = xplane[cur][(g * 2 + 0) * 64 + l];
      const float4 u1 = xplane[cur][(g * 2 + 1) * 64 + l];
      FragU ahi;
      ahi.u.x = pack2_bf_rnd(u0.x, u0.y);
      ahi.u.y = pack2_bf_rnd(u0.z, u0.w);
      ahi.u.z = pack2_bf_rnd(u1.x, u1.y);
      ahi.u.w = pack2_bf_rnd(u1.z, u1.w);
#pragma unroll
      for (int h = 0; h < 4; ++h) {
        acc[s][h] = __builtin_amdgcn_mfma_f32_16x16x32_bf16(ahi.f, bhi[h].f, acc[s][h], 0, 0, 0);
        acc[s][h] = __builtin_amdgcn_mfma_f32_16x16x32_bf16(ahi.f, blo[h].f, acc[s][h], 0, 0, 0);
      }
    }
    block_sync();   // all reads of buf[cur] done before it is restaged
  }

  // ---- epilogue: per-wave partial of relu(h+b1)@W2, cross-wave sum,
  //      w = exp(score) into wlds, block partial Z -> atomicAdd.
  float bvv[4], wvv[4];
#pragma unroll
  for (int h = 0; h < 4; ++h) {
    const int col = (cg * 4 + h) * 16 + lr;
    bvv[h] = b1[col];
    wvv[h] = W2[col];
  }
#pragma unroll
  for (int s = 0; s < 4; ++s) {
#pragma unroll
    for (int r = 0; r < 4; ++r) {
      float p = 0.0f;
#pragma unroll
      for (int h = 0; h < 4; ++h)
        p = fmaf(fmaxf(acc[s][h][r] + bvv[h], 0.0f), wvv[h], p);
#pragma unroll
      for (int off = 1; off < 16; off <<= 1) p += __shfl_xor(p, off, 64);
      if (lr == 0) sred[cg][rg * 64 + s * 16 + lg * 4 + r] = p;
    }
  }
  __syncthreads();
  if (cg == 0) {                      // waves 0 and 2 finalize 64 rows each
    const int row = rg * 64 + l;
    const int node = n0 + row;
    const float sc = sred[0][row] + sred[1][row] + b2[0];
    const float wgt = (node < N) ? __expf(sc) : 0.0f;
    wlds[row] = wgt;
    float zs = wgt;
#pragma unroll
    for (int off = 1; off < 64; off <<= 1) zs += __shfl_xor(zs, off, 64);
    if (l == 0) atomicAdd(zacc, zs);
  }
  __syncthreads();

  // ---- phase 2: pool own 128 rows (batch sorted); lane owns 4 columns ----
  {
    const int nStart = n0 + w * 32;
    const int nEnd = min(nStart + 32, N);
    if (nStart < nEnd) {
      float4 a4 = make_float4(0.f, 0.f, 0.f, 0.f);
      int bprev = batch[nStart];
      for (int n = nStart; n < nEnd; ++n) {
        const int b = batch[n];
        if (b != bprev) {
          float* o = out + (size_t)bprev * D + l * 4;
          atomicAdd(o + 0, a4.x); atomicAdd(o + 1, a4.y);
          atomicAdd(o + 2, a4.z); atomicAdd(o + 3, a4.w);
          a4 = make_float4(0.f, 0.f, 0.f, 0.f);
          bprev = b;
        }
        const float wgt = wlds[n - n0];
        const float4 xv = *reinterpret_cast<const float4*>(x + (size_t)n * D + l * 4);
        a4.x = fmaf(xv.x, wgt, a4.x);
        a4.y = fmaf(xv.y, wgt, a4.y);
        a4.z = fmaf(xv.z, wgt, a4.z);
        a4.w = fmaf(xv.w, wgt, a4.w);
      }
      float* o = out + (size_t)bprev * D + l * 4;
      atomicAdd(o + 0, a4.x); atomicAdd(o + 1, a4.y);
      atomicAdd(o + 2, a4.z); atomicAdd(o + 3, a4.w);
    }
  }
}

// ---- finish: out *= 1/Z ----------------------------------------------------
extern "C" __global__ void __launch_bounds__(256)
k_finish(float* __restrict__ out, const float* __restrict__ zacc, int size)
{
  const int i = blockIdx.x * 256 + threadIdx.x;
  if (i < size) out[i] *= (1.0f / *zacc);
}

extern "C" void kernel_launch(void* const* d_in, const int* in_sizes, int n_in,
                              void* d_out, int out_size, void* d_ws, size_t ws_size,
                              hipStream_t stream)
{
  const float* x     = (const float*)d_in[0];
  const int*   batch = (const int*)d_in[1];
  const float* W1 = (const float*)d_in[3];
  const float* b1 = (const float*)d_in[4];
  const float* W2 = (const float*)d_in[5];
  const float* b2 = (const float*)d_in[6];
  const int N = in_sizes[1];

  float* zacc = (float*)d_ws;
  uint4* phi  = (uint4*)((char*)d_ws + 256);            // 64 KB
  uint4* plo  = (uint4*)((char*)d_ws + 256 + 65536);    // 64 KB

  k_init<<<(out_size + 255) / 256, 256, 0, stream>>>((float*)d_out, out_size, zacc);
  k_pack<<<16, 256, 0, stream>>>(W1, phi, plo);

  const int g1 = (N + BM - 1) / BM;
  k_fused<<<g1, 256, 0, stream>>>(x, batch, phi, plo, b1, W2, b2,
                                  (float*)d_out, zacc, N);

  k_finish<<<(out_size + 255) / 256, 256, 0, stream>>>((float*)d_out, zacc, out_size);
}